// Round 1
// baseline (170.122 us; speedup 1.0000x reference)
//
#include <hip/hip_runtime.h>
#include <math.h>

#define MAGB 0.01f

__device__ __forceinline__ int refl(int i, int n) {
  // symmetric reflection: -1 -> 0, -2 -> 1, n -> n-1, n+1 -> n-2
  if (i < 0) i = -1 - i;
  if (i >= n) i = 2 * n - 1 - i;
  return i;
}

__device__ __forceinline__ float magf(float re, float im) {
  return sqrtf(re * re + im * im + MAGB * MAGB) - MAGB;
}

// ---------------- Stage A/C kernel 1: row filter along W (5-tap h0, 7-tap h1)
__global__ void k_rowfilt(const float* __restrict__ x,
                          const float* __restrict__ h0,
                          const float* __restrict__ h1,
                          float* __restrict__ lo,
                          float* __restrict__ hi,
                          int total, int W) {
  int idx = blockIdx.x * blockDim.x + threadIdx.x;
  if (idx >= total) return;
  int w = idx % W;
  int rowi = idx / W;
  const float* row = x + (size_t)rowi * W;
  float a0 = 0.f, a1 = 0.f;
#pragma unroll
  for (int j = 0; j < 5; ++j) a0 += h0[j] * row[refl(w - 2 + j, W)];
#pragma unroll
  for (int j = 0; j < 7; ++j) a1 += h1[j] * row[refl(w - 3 + j, W)];
  lo[idx] = a0;
  hi[idx] = a1;
}

// ---------------- Stage A kernel 2: col filter + q2c + mag; writes full-res ll
// to s0 and the 6 orientation magnitudes to pb laid out (N, 6*C, H/2, W/2).
__global__ void k_colmag_j1a(const float* __restrict__ lo,
                             const float* __restrict__ hi,
                             const float* __restrict__ h0,
                             const float* __restrict__ h1,
                             float* __restrict__ s0,
                             float* __restrict__ pb,
                             int P, int C, int H, int W) {
  int H2 = H >> 1, W2 = W >> 1;
  int idx = blockIdx.x * blockDim.x + threadIdx.x;
  int total = P * H2 * W2;
  if (idx >= total) return;
  int w2 = idx % W2;
  int t = idx / W2;
  int h2 = t % H2;
  int p = t / H2;
  int n = p / C, ch = p % C;
  const float* bl = lo + (size_t)p * H * W;
  const float* bh = hi + (size_t)p * H * W;
  float* bs = s0 + (size_t)p * H * W;
  float lhv[2][2], hlv[2][2], hhv[2][2];
  int rb = 2 * h2 - 3;
#pragma unroll
  for (int dc = 0; dc < 2; ++dc) {
    int c = 2 * w2 + dc;
    float vl[8], vh[8];
#pragma unroll
    for (int tt = 0; tt < 8; ++tt) {
      int rr = refl(rb + tt, H);
      vl[tt] = bl[(size_t)rr * W + c];
      vh[tt] = bh[(size_t)rr * W + c];
    }
#pragma unroll
    for (int dr = 0; dr < 2; ++dr) {
      float sll = 0.f, slh = 0.f, shl = 0.f, shh = 0.f;
#pragma unroll
      for (int j = 0; j < 5; ++j) {
        sll += h0[j] * vl[dr + 1 + j];
        shl += h0[j] * vh[dr + 1 + j];
      }
#pragma unroll
      for (int j = 0; j < 7; ++j) {
        slh += h1[j] * vl[dr + j];
        shh += h1[j] * vh[dr + j];
      }
      bs[(size_t)(2 * h2 + dr) * W + c] = sll;
      lhv[dr][dc] = slh; hlv[dr][dc] = shl; hhv[dr][dc] = shh;
    }
  }
  float m[6];
  { float a = lhv[0][0], b = lhv[0][1], cc = lhv[1][0], d = lhv[1][1];
    m[0] = magf((a + d) * 0.5f, (b - cc) * 0.5f);
    m[5] = magf((a - d) * 0.5f, (b + cc) * 0.5f); }
  { float a = hhv[0][0], b = hhv[0][1], cc = hhv[1][0], d = hhv[1][1];
    m[1] = magf((a + d) * 0.5f, (b - cc) * 0.5f);
    m[4] = magf((a - d) * 0.5f, (b + cc) * 0.5f); }
  { float a = hlv[0][0], b = hlv[0][1], cc = hlv[1][0], d = hlv[1][1];
    m[2] = magf((a + d) * 0.5f, (b - cc) * 0.5f);
    m[3] = magf((a - d) * 0.5f, (b + cc) * 0.5f); }
#pragma unroll
  for (int o = 0; o < 6; ++o) {
    pb[(((size_t)n * (6 * C) + (size_t)(o * C + ch)) * H2 + h2) * W2 + w2] = m[o];
  }
}

// ---------------- Stage B kernel 3: row dfilt (q-shift level-2) along W.
// One thread per output pair-of-pairs: writes lo2/hi2 at cols 2i, 2i+1.
__global__ void k_rowdfilt(const float* __restrict__ x,
                           const float* __restrict__ h0a,
                           const float* __restrict__ h0b,
                           const float* __restrict__ h1a,
                           const float* __restrict__ h1b,
                           float* __restrict__ lo2,
                           float* __restrict__ hi2,
                           int P, int H, int W) {
  int Wq = W >> 2, Wh = W >> 1;
  int idx = blockIdx.x * blockDim.x + threadIdx.x;
  int total = P * H * Wq;
  if (idx >= total) return;
  int i = idx % Wq;
  int t = idx / Wq;
  int h = t % H;
  int p = t / H;
  const float* row = x + ((size_t)p * H + h) * W;
  float v[20];
#pragma unroll
  for (int tt = 0; tt < 20; ++tt) v[tt] = row[refl(4 * i - 8 + tt, W)];
  float ya0 = 0.f, yb0 = 0.f, ya1 = 0.f, yb1 = 0.f;
#pragma unroll
  for (int j = 0; j < 10; ++j) {
    ya0 += h0a[j] * v[2 * j];
    yb0 += h0b[j] * v[2 * j + 1];
    ya1 += h1a[j] * v[2 * j];
    yb1 += h1b[j] * v[2 * j + 1];
  }
  float* lrow = lo2 + ((size_t)p * H + h) * Wh;
  float* hrow = hi2 + ((size_t)p * H + h) * Wh;
  lrow[2 * i] = ya0;      // lowpass: first=ya
  lrow[2 * i + 1] = yb0;
  hrow[2 * i] = yb1;      // highpass: first=yb
  hrow[2 * i + 1] = ya1;
}

// ---------------- Stage B kernel 4: col dfilt + q2c + mag + avgpool -> out.
__global__ void k_coldfilt_mag(const float* __restrict__ lo2,
                               const float* __restrict__ hi2,
                               const float* __restrict__ h0a,
                               const float* __restrict__ h0b,
                               const float* __restrict__ h1a,
                               const float* __restrict__ h1b,
                               float* __restrict__ out,
                               int P, int C, int H, int Wh) {
  int H4 = H >> 2, W4 = Wh >> 1;
  int idx = blockIdx.x * blockDim.x + threadIdx.x;
  int total = P * H4 * W4;
  if (idx >= total) return;
  int w4 = idx % W4;
  int t = idx / W4;
  int h4 = t % H4;
  int p = t / H4;
  int n = p / C, ch = p % C;
  const float* bl = lo2 + (size_t)p * H * Wh;
  const float* bh = hi2 + (size_t)p * H * Wh;
  float llv[2][2], lhv[2][2], hlv[2][2], hhv[2][2];
#pragma unroll
  for (int dc = 0; dc < 2; ++dc) {
    int c = 2 * w4 + dc;
    float vl[20], vh[20];
#pragma unroll
    for (int tt = 0; tt < 20; ++tt) {
      int rr = refl(4 * h4 - 8 + tt, H);
      vl[tt] = bl[(size_t)rr * Wh + c];
      vh[tt] = bh[(size_t)rr * Wh + c];
    }
    float a0l = 0.f, b0l = 0.f, a1l = 0.f, b1l = 0.f;
    float a0h = 0.f, b0h = 0.f, a1h = 0.f, b1h = 0.f;
#pragma unroll
    for (int j = 0; j < 10; ++j) {
      float ve_l = vl[2 * j], vo_l = vl[2 * j + 1];
      float ve_h = vh[2 * j], vo_h = vh[2 * j + 1];
      a0l += h0a[j] * ve_l; b0l += h0b[j] * vo_l;
      a1l += h1a[j] * ve_l; b1l += h1b[j] * vo_l;
      a0h += h0a[j] * ve_h; b0h += h0b[j] * vo_h;
      a1h += h1a[j] * ve_h; b1h += h1b[j] * vo_h;
    }
    llv[0][dc] = a0l; llv[1][dc] = b0l;   // lowpass: rows 2i -> ya, 2i+1 -> yb
    lhv[0][dc] = b1l; lhv[1][dc] = a1l;   // highpass: rows 2i -> yb, 2i+1 -> ya
    hlv[0][dc] = a0h; hlv[1][dc] = b0h;
    hhv[0][dc] = b1h; hhv[1][dc] = a1h;
  }
  size_t sp = (size_t)H4 * W4;
  float* ob = out + (size_t)n * 147 * sp + (size_t)h4 * W4 + w4;
  // pooled ll -> q = ch
  ob[(size_t)ch * sp] = 0.25f * (llv[0][0] + llv[0][1] + llv[1][0] + llv[1][1]);
  float m[6];
  { float a = lhv[0][0], b = lhv[0][1], cc = lhv[1][0], d = lhv[1][1];
    m[0] = magf((a + d) * 0.5f, (b - cc) * 0.5f);
    m[5] = magf((a - d) * 0.5f, (b + cc) * 0.5f); }
  { float a = hhv[0][0], b = hhv[0][1], cc = hhv[1][0], d = hhv[1][1];
    m[1] = magf((a + d) * 0.5f, (b - cc) * 0.5f);
    m[4] = magf((a - d) * 0.5f, (b + cc) * 0.5f); }
  { float a = hlv[0][0], b = hlv[0][1], cc = hlv[1][0], d = hlv[1][1];
    m[2] = magf((a + d) * 0.5f, (b - cc) * 0.5f);
    m[3] = magf((a - d) * 0.5f, (b + cc) * 0.5f); }
#pragma unroll
  for (int o = 0; o < 6; ++o) {
    ob[(size_t)((7 + o) * 3 + ch) * sp] = m[o];
  }
}

// ---------------- Stage C kernel 6: col filter + q2c + mag + pooled ll -> out.
__global__ void k_colmag_j1c(const float* __restrict__ lo,
                             const float* __restrict__ hi,
                             const float* __restrict__ h0,
                             const float* __restrict__ h1,
                             float* __restrict__ out,
                             int P, int H, int W) {
  int H2 = H >> 1, W2 = W >> 1;
  int idx = blockIdx.x * blockDim.x + threadIdx.x;
  int total = P * H2 * W2;
  if (idx >= total) return;
  int w2 = idx % W2;
  int t = idx / W2;
  int h2 = t % H2;
  int p = t / H2;
  int c18 = p % 18;
  int n = p / 18;
  int o1 = c18 / 3, ch = c18 % 3;
  const float* bl = lo + (size_t)p * H * W;
  const float* bh = hi + (size_t)p * H * W;
  float llv[2][2], lhv[2][2], hlv[2][2], hhv[2][2];
  int rb = 2 * h2 - 3;
#pragma unroll
  for (int dc = 0; dc < 2; ++dc) {
    int c = 2 * w2 + dc;
    float vl[8], vh[8];
#pragma unroll
    for (int tt = 0; tt < 8; ++tt) {
      int rr = refl(rb + tt, H);
      vl[tt] = bl[(size_t)rr * W + c];
      vh[tt] = bh[(size_t)rr * W + c];
    }
#pragma unroll
    for (int dr = 0; dr < 2; ++dr) {
      float sll = 0.f, slh = 0.f, shl = 0.f, shh = 0.f;
#pragma unroll
      for (int j = 0; j < 5; ++j) {
        sll += h0[j] * vl[dr + 1 + j];
        shl += h0[j] * vh[dr + 1 + j];
      }
#pragma unroll
      for (int j = 0; j < 7; ++j) {
        slh += h1[j] * vl[dr + j];
        shh += h1[j] * vh[dr + j];
      }
      llv[dr][dc] = sll; lhv[dr][dc] = slh; hlv[dr][dc] = shl; hhv[dr][dc] = shh;
    }
  }
  size_t sp = (size_t)H2 * W2;
  float* ob = out + (size_t)n * 147 * sp + (size_t)h2 * W2 + w2;
  // pooled ll -> q = (1+o1)*3 + ch
  ob[(size_t)((1 + o1) * 3 + ch) * sp] =
      0.25f * (llv[0][0] + llv[0][1] + llv[1][0] + llv[1][1]);
  float m[6];
  { float a = lhv[0][0], b = lhv[0][1], cc = lhv[1][0], d = lhv[1][1];
    m[0] = magf((a + d) * 0.5f, (b - cc) * 0.5f);
    m[5] = magf((a - d) * 0.5f, (b + cc) * 0.5f); }
  { float a = hhv[0][0], b = hhv[0][1], cc = hhv[1][0], d = hhv[1][1];
    m[1] = magf((a + d) * 0.5f, (b - cc) * 0.5f);
    m[4] = magf((a - d) * 0.5f, (b + cc) * 0.5f); }
  { float a = hlv[0][0], b = hlv[0][1], cc = hlv[1][0], d = hlv[1][1];
    m[2] = magf((a + d) * 0.5f, (b - cc) * 0.5f);
    m[3] = magf((a - d) * 0.5f, (b + cc) * 0.5f); }
#pragma unroll
  for (int o2 = 0; o2 < 6; ++o2) {
    ob[(size_t)((13 + o2 * 6 + o1) * 3 + ch) * sp] = m[o2];
  }
}

extern "C" void kernel_launch(void* const* d_in, const int* in_sizes, int n_in,
                              void* d_out, int out_size, void* d_ws, size_t ws_size,
                              hipStream_t stream) {
  const float* x   = (const float*)d_in[0];
  const float* h0o = (const float*)d_in[1];
  const float* h1o = (const float*)d_in[2];
  const float* h0a = (const float*)d_in[3];
  const float* h0b = (const float*)d_in[4];
  const float* h1a = (const float*)d_in[5];
  const float* h1b = (const float*)d_in[6];
  float* out = (float*)d_out;
  char* ws = (char*)d_ws;

  const int N = 8, C = 3, H = 512, W = 512;

  // Workspace regions (aliased across phases):
  // R1: lo (24x512x512) | lo2 (24x512x256) | lo3 (144x256x256)  -> 37.75 MB
  // R2: hi               | hi2              | hi3               -> 37.75 MB
  // R3: s0 (24x512x512)                                          -> 25.17 MB
  // R4: pb (8x18x256x256)                                        -> 37.75 MB
  const size_t SZ_BIG = (size_t)144 * 256 * 256 * sizeof(float); // 37748736
  const size_t SZ_S0  = (size_t)N * C * H * W * sizeof(float);   // 25165824
  float* lo = (float*)(ws);
  float* hi = (float*)(ws + SZ_BIG);
  float* s0 = (float*)(ws + 2 * SZ_BIG);
  float* pb = (float*)(ws + 2 * SZ_BIG + SZ_S0);
  (void)ws_size; (void)in_sizes; (void)n_in; (void)out_size;

  const int BLK = 256;

  // Stage A: j1 on x
  {
    int total = N * C * H * W;                       // 6291456
    k_rowfilt<<<(total + BLK - 1) / BLK, BLK, 0, stream>>>(x, h0o, h1o, lo, hi, total, W);
    int total2 = N * C * (H / 2) * (W / 2);          // 1572864
    k_colmag_j1a<<<(total2 + BLK - 1) / BLK, BLK, 0, stream>>>(
        lo, hi, h0o, h1o, s0, pb, N * C, C, H, W);
  }
  // Stage B: j2 on s0
  {
    int total3 = N * C * H * (W / 4);                // 1572864
    k_rowdfilt<<<(total3 + BLK - 1) / BLK, BLK, 0, stream>>>(
        s0, h0a, h0b, h1a, h1b, lo, hi, N * C, H, W);
    int total4 = N * C * (H / 4) * (W / 4);          // 393216
    k_coldfilt_mag<<<(total4 + BLK - 1) / BLK, BLK, 0, stream>>>(
        lo, hi, h0a, h0b, h1a, h1b, out, N * C, C, H, W / 2);
  }
  // Stage C: j1 on pb
  {
    int total5 = N * 18 * 256 * 256;                 // 9437184
    k_rowfilt<<<(total5 + BLK - 1) / BLK, BLK, 0, stream>>>(pb, h0o, h1o, lo, hi, total5, 256);
    int total6 = N * 18 * 128 * 128;                 // 2359296
    k_colmag_j1c<<<(total6 + BLK - 1) / BLK, BLK, 0, stream>>>(
        lo, hi, h0o, h1o, out, N * 18, 256, 256);
  }
}

// Round 2
// 108.673 us; speedup vs baseline: 1.5654x; 1.5654x over previous
//
#include <hip/hip_runtime.h>
#include <math.h>

#define MAGB 0.01f

__device__ __forceinline__ int refl(int i, int n) {
  if (i < 0) i = -1 - i;
  if (i >= n) i = 2 * n - 1 - i;
  return i;
}

__device__ __forceinline__ float magf(float re, float im) {
  return sqrtf(re * re + im * im + MAGB * MAGB) - MAGB;
}

// q2c of a 2x2 quad -> two magnitudes (lo-orientation, hi-orientation)
__device__ __forceinline__ void q2c_mag(const float v[2][2], float* mlo, float* mhi) {
  float a = v[0][0], b = v[0][1], c = v[1][0], d = v[1][1];
  *mlo = magf((a + d) * 0.5f, (b - c) * 0.5f);
  *mhi = magf((a - d) * 0.5f, (b + c) * 0.5f);
}

// ---------------------------------------------------------------------------
// Fused j1 stage A: rowfilt -> LDS, colfilt + q2c + mag; writes full-res ll
// (s0) and 6 orientation mags to pb (N, 6*C, H/2, W/2).
// Tile: half-res 16x32  (full-res 32x64). Block 256.
// ---------------------------------------------------------------------------
#define TA_H2 16
#define TA_W2 32
#define TA_RF 38
#define TA_W 64
#define TA_PAD 65

__global__ __launch_bounds__(256) void k_fused_j1a(
    const float* __restrict__ x,
    const float* __restrict__ h0, const float* __restrict__ h1,
    float* __restrict__ s0, float* __restrict__ pb,
    int C, int H, int W) {
  __shared__ float lo_s[TA_RF][TA_PAD];
  __shared__ float hi_s[TA_RF][TA_PAD];
  int H2 = H >> 1, W2 = W >> 1;
  int tilesW = W2 / TA_W2;
  int tilesH = H2 / TA_H2;
  int tiles = tilesW * tilesH;
  int p = blockIdx.x / tiles;
  int tloc = blockIdx.x % tiles;
  int th = tloc / tilesW, tw = tloc % tilesW;
  int h2_0 = th * TA_H2, w2_0 = tw * TA_W2;
  int c0 = 2 * w2_0;
  const float* xp = x + (size_t)p * H * W;
  float f0[5], f1[7];
#pragma unroll
  for (int j = 0; j < 5; ++j) f0[j] = h0[j];
#pragma unroll
  for (int j = 0; j < 7; ++j) f1[j] = h1[j];

  int tid = threadIdx.x;
  bool interior = (c0 >= 3) && (c0 + TA_W + 3 <= W);
  // Phase 1: row filter into LDS
  for (int e = tid; e < TA_RF * TA_W; e += 256) {
    int rr = e / TA_W, cc = e % TA_W;
    int row = refl(2 * h2_0 - 3 + rr, H);
    const float* xr = xp + (size_t)row * W;
    int c = c0 + cc;
    float a0 = 0.f, a1 = 0.f;
    if (interior) {
#pragma unroll
      for (int j = 0; j < 5; ++j) a0 += f0[j] * xr[c - 2 + j];
#pragma unroll
      for (int j = 0; j < 7; ++j) a1 += f1[j] * xr[c - 3 + j];
    } else {
#pragma unroll
      for (int j = 0; j < 5; ++j) a0 += f0[j] * xr[refl(c - 2 + j, W)];
#pragma unroll
      for (int j = 0; j < 7; ++j) a1 += f1[j] * xr[refl(c - 3 + j, W)];
    }
    lo_s[rr][cc] = a0;
    hi_s[rr][cc] = a1;
  }
  __syncthreads();

  // Phase 2: column filter + q2c + mag
  float* s0p = s0 + (size_t)p * H * W;
  int n = p / C, ch = p % C;
  size_t sp2 = (size_t)H2 * W2;
  float* pbb = pb + (size_t)n * (6 * C) * sp2;
  for (int o = tid; o < TA_H2 * TA_W2; o += 256) {
    int h2l = o / TA_W2, w2l = o % TA_W2;
    int h2 = h2_0 + h2l, w2 = w2_0 + w2l;
    float llq[2][2], lhv[2][2], hlv[2][2], hhv[2][2];
#pragma unroll
    for (int dc = 0; dc < 2; ++dc) {
      int cl = 2 * w2l + dc;
      float vl[8], vh[8];
#pragma unroll
      for (int tt = 0; tt < 8; ++tt) {
        vl[tt] = lo_s[2 * h2l + tt][cl];
        vh[tt] = hi_s[2 * h2l + tt][cl];
      }
#pragma unroll
      for (int dr = 0; dr < 2; ++dr) {
        float sll = 0.f, slh = 0.f, shl = 0.f, shh = 0.f;
#pragma unroll
        for (int j = 0; j < 5; ++j) {
          sll += f0[j] * vl[dr + 1 + j];
          shl += f0[j] * vh[dr + 1 + j];
        }
#pragma unroll
        for (int j = 0; j < 7; ++j) {
          slh += f1[j] * vl[dr + j];
          shh += f1[j] * vh[dr + j];
        }
        llq[dr][dc] = sll; lhv[dr][dc] = slh; hlv[dr][dc] = shl; hhv[dr][dc] = shh;
      }
    }
#pragma unroll
    for (int dr = 0; dr < 2; ++dr) {
      float2 v = make_float2(llq[dr][0], llq[dr][1]);
      *(float2*)&s0p[(size_t)(2 * h2 + dr) * W + 2 * w2] = v;
    }
    float m[6];
    q2c_mag(lhv, &m[0], &m[5]);
    q2c_mag(hhv, &m[1], &m[4]);
    q2c_mag(hlv, &m[2], &m[3]);
#pragma unroll
    for (int o6 = 0; o6 < 6; ++o6) {
      pbb[(size_t)(o6 * C + ch) * sp2 + (size_t)h2 * W2 + w2] = m[o6];
    }
  }
}

// ---------------------------------------------------------------------------
// Fused j2 stage B: row dfilt -> LDS, col dfilt + q2c + mag + pooled ll -> out
// Tile: quarter-res 16x16. Block 256.
// ---------------------------------------------------------------------------
#define TB 16
#define TB_R 80
#define TB_PAD 33

__global__ __launch_bounds__(256) void k_fused_j2(
    const float* __restrict__ s0,
    const float* __restrict__ h0a, const float* __restrict__ h0b,
    const float* __restrict__ h1a, const float* __restrict__ h1b,
    float* __restrict__ out, int C, int H, int W) {
  __shared__ float lo2_s[TB_R][TB_PAD];
  __shared__ float hi2_s[TB_R][TB_PAD];
  int H4 = H >> 2, W4 = W >> 2;
  int tilesW = W4 / TB;
  int tiles = tilesW * (H4 / TB);
  int p = blockIdx.x / tiles;
  int tloc = blockIdx.x % tiles;
  int th = tloc / tilesW, tw = tloc % tilesW;
  int h4_0 = th * TB, w4_0 = tw * TB;
  const float* sp = s0 + (size_t)p * H * W;
  float fa0[10], fb0[10], fa1[10], fb1[10];
#pragma unroll
  for (int j = 0; j < 10; ++j) {
    fa0[j] = h0a[j]; fb0[j] = h0b[j]; fa1[j] = h1a[j]; fb1[j] = h1b[j];
  }
  int tid = threadIdx.x;
  bool interior = (4 * w4_0 - 8 >= 0) && (4 * (w4_0 + TB - 1) + 11 < W);
  // Phase 1: row dfilt into LDS (80 rows x 16 col-pairs)
  for (int e = tid; e < TB_R * TB; e += 256) {
    int hr = e / TB, il = e % TB;
    int row = refl(4 * h4_0 - 8 + hr, H);
    const float* xr = sp + (size_t)row * W;
    int i = w4_0 + il;
    float ya0 = 0.f, yb0 = 0.f, ya1 = 0.f, yb1 = 0.f;
    if (interior) {
      const float* xb = xr + 4 * i - 8;
#pragma unroll
      for (int j = 0; j < 10; ++j) {
        float ve = xb[2 * j], vo = xb[2 * j + 1];
        ya0 += fa0[j] * ve; yb0 += fb0[j] * vo;
        ya1 += fa1[j] * ve; yb1 += fb1[j] * vo;
      }
    } else {
#pragma unroll
      for (int j = 0; j < 10; ++j) {
        float ve = xr[refl(4 * i - 8 + 2 * j, W)];
        float vo = xr[refl(4 * i - 7 + 2 * j, W)];
        ya0 += fa0[j] * ve; yb0 += fb0[j] * vo;
        ya1 += fa1[j] * ve; yb1 += fb1[j] * vo;
      }
    }
    lo2_s[hr][2 * il] = ya0;
    lo2_s[hr][2 * il + 1] = yb0;
    hi2_s[hr][2 * il] = yb1;     // highpass: first=yb
    hi2_s[hr][2 * il + 1] = ya1;
  }
  __syncthreads();

  // Phase 2: col dfilt + q2c + mag + pooled ll (one output per thread)
  {
    int h4l = tid / TB, w4l = tid % TB;
    int h4 = h4_0 + h4l, w4 = w4_0 + w4l;
    float llv[2][2], lhv[2][2], hlv[2][2], hhv[2][2];
#pragma unroll
    for (int dc = 0; dc < 2; ++dc) {
      int cl = 2 * w4l + dc;
      float a0l = 0.f, b0l = 0.f, a1l = 0.f, b1l = 0.f;
      float a0h = 0.f, b0h = 0.f, a1h = 0.f, b1h = 0.f;
#pragma unroll
      for (int j = 0; j < 10; ++j) {
        int hre = 4 * h4l + 2 * j;
        float vel = lo2_s[hre][cl], vol = lo2_s[hre + 1][cl];
        float veh = hi2_s[hre][cl], voh = hi2_s[hre + 1][cl];
        a0l += fa0[j] * vel; b0l += fb0[j] * vol;
        a1l += fa1[j] * vel; b1l += fb1[j] * vol;
        a0h += fa0[j] * veh; b0h += fb0[j] * voh;
        a1h += fa1[j] * veh; b1h += fb1[j] * voh;
      }
      llv[0][dc] = a0l; llv[1][dc] = b0l;  // lowpass: rows 2i->ya, 2i+1->yb
      lhv[0][dc] = b1l; lhv[1][dc] = a1l;  // highpass: rows 2i->yb, 2i+1->ya
      hlv[0][dc] = a0h; hlv[1][dc] = b0h;
      hhv[0][dc] = b1h; hhv[1][dc] = a1h;
    }
    int n = p / C, ch = p % C;
    size_t spo = (size_t)H4 * W4;
    float* ob = out + (size_t)n * 147 * spo + (size_t)h4 * W4 + w4;
    ob[(size_t)ch * spo] =
        0.25f * (llv[0][0] + llv[0][1] + llv[1][0] + llv[1][1]);
    float m[6];
    q2c_mag(lhv, &m[0], &m[5]);
    q2c_mag(hhv, &m[1], &m[4]);
    q2c_mag(hlv, &m[2], &m[3]);
#pragma unroll
    for (int o = 0; o < 6; ++o) {
      ob[(size_t)((7 + o) * 3 + ch) * spo] = m[o];
    }
  }
}

// ---------------------------------------------------------------------------
// Fused j1 stage C: rowfilt -> LDS, colfilt + q2c + mag + pooled ll -> out
// Input pb (8, 18, 256, 256). Tile: half-res 16x32. Block 256.
// ---------------------------------------------------------------------------
__global__ __launch_bounds__(256) void k_fused_j1c(
    const float* __restrict__ pb,
    const float* __restrict__ h0, const float* __restrict__ h1,
    float* __restrict__ out, int H, int W) {
  __shared__ float lo_s[TA_RF][TA_PAD];
  __shared__ float hi_s[TA_RF][TA_PAD];
  int H2 = H >> 1, W2 = W >> 1;
  int tilesW = W2 / TA_W2;
  int tiles = tilesW * (H2 / TA_H2);
  int p = blockIdx.x / tiles;
  int tloc = blockIdx.x % tiles;
  int th = tloc / tilesW, tw = tloc % tilesW;
  int h2_0 = th * TA_H2, w2_0 = tw * TA_W2;
  int c0 = 2 * w2_0;
  const float* xp = pb + (size_t)p * H * W;
  float f0[5], f1[7];
#pragma unroll
  for (int j = 0; j < 5; ++j) f0[j] = h0[j];
#pragma unroll
  for (int j = 0; j < 7; ++j) f1[j] = h1[j];

  int tid = threadIdx.x;
  bool interior = (c0 >= 3) && (c0 + TA_W + 3 <= W);
  for (int e = tid; e < TA_RF * TA_W; e += 256) {
    int rr = e / TA_W, cc = e % TA_W;
    int row = refl(2 * h2_0 - 3 + rr, H);
    const float* xr = xp + (size_t)row * W;
    int c = c0 + cc;
    float a0 = 0.f, a1 = 0.f;
    if (interior) {
#pragma unroll
      for (int j = 0; j < 5; ++j) a0 += f0[j] * xr[c - 2 + j];
#pragma unroll
      for (int j = 0; j < 7; ++j) a1 += f1[j] * xr[c - 3 + j];
    } else {
#pragma unroll
      for (int j = 0; j < 5; ++j) a0 += f0[j] * xr[refl(c - 2 + j, W)];
#pragma unroll
      for (int j = 0; j < 7; ++j) a1 += f1[j] * xr[refl(c - 3 + j, W)];
    }
    lo_s[rr][cc] = a0;
    hi_s[rr][cc] = a1;
  }
  __syncthreads();

  int c18 = p % 18, n = p / 18;
  int o1 = c18 / 3, ch = c18 % 3;
  size_t spo = (size_t)H2 * W2;
  float* ob = out + (size_t)n * 147 * spo;
  for (int o = tid; o < TA_H2 * TA_W2; o += 256) {
    int h2l = o / TA_W2, w2l = o % TA_W2;
    int h2 = h2_0 + h2l, w2 = w2_0 + w2l;
    float llq[2][2], lhv[2][2], hlv[2][2], hhv[2][2];
#pragma unroll
    for (int dc = 0; dc < 2; ++dc) {
      int cl = 2 * w2l + dc;
      float vl[8], vh[8];
#pragma unroll
      for (int tt = 0; tt < 8; ++tt) {
        vl[tt] = lo_s[2 * h2l + tt][cl];
        vh[tt] = hi_s[2 * h2l + tt][cl];
      }
#pragma unroll
      for (int dr = 0; dr < 2; ++dr) {
        float sll = 0.f, slh = 0.f, shl = 0.f, shh = 0.f;
#pragma unroll
        for (int j = 0; j < 5; ++j) {
          sll += f0[j] * vl[dr + 1 + j];
          shl += f0[j] * vh[dr + 1 + j];
        }
#pragma unroll
        for (int j = 0; j < 7; ++j) {
          slh += f1[j] * vl[dr + j];
          shh += f1[j] * vh[dr + j];
        }
        llq[dr][dc] = sll; lhv[dr][dc] = slh; hlv[dr][dc] = shl; hhv[dr][dc] = shh;
      }
    }
    size_t px = (size_t)h2 * W2 + w2;
    ob[(size_t)((1 + o1) * 3 + ch) * spo + px] =
        0.25f * (llq[0][0] + llq[0][1] + llq[1][0] + llq[1][1]);
    float m[6];
    q2c_mag(lhv, &m[0], &m[5]);
    q2c_mag(hhv, &m[1], &m[4]);
    q2c_mag(hlv, &m[2], &m[3]);
#pragma unroll
    for (int o2 = 0; o2 < 6; ++o2) {
      ob[(size_t)((13 + o2 * 6 + o1) * 3 + ch) * spo + px] = m[o2];
    }
  }
}

extern "C" void kernel_launch(void* const* d_in, const int* in_sizes, int n_in,
                              void* d_out, int out_size, void* d_ws, size_t ws_size,
                              hipStream_t stream) {
  const float* x   = (const float*)d_in[0];
  const float* h0o = (const float*)d_in[1];
  const float* h1o = (const float*)d_in[2];
  const float* h0a = (const float*)d_in[3];
  const float* h0b = (const float*)d_in[4];
  const float* h1a = (const float*)d_in[5];
  const float* h1b = (const float*)d_in[6];
  float* out = (float*)d_out;
  char* ws = (char*)d_ws;
  (void)in_sizes; (void)n_in; (void)out_size; (void)ws_size;

  const int N = 8, C = 3, H = 512, W = 512;

  // Workspace: s0 (24x512x512 f32 = 24 MB), pb (8x18x256x256 f32 = 37.75 MB)
  const size_t SZ_S0 = (size_t)N * C * H * W * sizeof(float);
  float* s0 = (float*)ws;
  float* pb = (float*)(ws + SZ_S0);

  // Stage A: fused j1 on x -> s0 (full-res ll), pb (6 orientation mags)
  {
    int tiles = (H / 2 / TA_H2) * (W / 2 / TA_W2);  // 16*8 = 128
    int blocks = N * C * tiles;                      // 3072
    k_fused_j1a<<<blocks, 256, 0, stream>>>(x, h0o, h1o, s0, pb, C, H, W);
  }
  // Stage B: fused j2 on s0 -> out (pooled ll q=ch, mags q=(7+o)*3+ch)
  {
    int tiles = (H / 4 / TB) * (W / 4 / TB);         // 8*8 = 64
    int blocks = N * C * tiles;                      // 1536
    k_fused_j2<<<blocks, 256, 0, stream>>>(s0, h0a, h0b, h1a, h1b, out, C, H, W);
  }
  // Stage C: fused j1 on pb -> out (pooled ll q=(1+o1)*3+ch, s2 mags)
  {
    int tiles = (256 / 2 / TA_H2) * (256 / 2 / TA_W2);  // 8*4 = 32
    int blocks = N * 18 * tiles;                         // 4608
    k_fused_j1c<<<blocks, 256, 0, stream>>>(pb, h0o, h1o, out, 256, 256);
  }
}

// Round 3
// 80.614 us; speedup vs baseline: 2.1103x; 1.3481x over previous
//
#include <hip/hip_runtime.h>
#include <math.h>

#define MAGB 0.01f

__device__ __forceinline__ int refl(int i, int n) {
  if (i < 0) i = -1 - i;
  if (i >= n) i = 2 * n - 1 - i;
  return i;
}

__device__ __forceinline__ float magf(float re, float im) {
  return sqrtf(re * re + im * im + MAGB * MAGB) - MAGB;
}

__device__ __forceinline__ void q2c_mag(const float v[2][2], float* mlo, float* mhi) {
  float a = v[0][0], b = v[0][1], c = v[1][0], d = v[1][1];
  *mlo = magf((a + d) * 0.5f, (b - c) * 0.5f);
  *mhi = magf((a - d) * 0.5f, (b + c) * 0.5f);
}

// Row-filter 4 adjacent outputs (cols cb..cb+3) for 5-tap f0 and 7-tap f1.
// Needs input cols [cb-3, cb+6]; interior path = 3 aligned float4 loads.
__device__ __forceinline__ void rowfilt4(const float* __restrict__ xr, int cb, int Wd,
                                         const float* __restrict__ f0,
                                         const float* __restrict__ f1,
                                         float* o0, float* o1) {
  float v[12];
  if (cb >= 4 && cb + 8 <= Wd) {
    float4 a = *(const float4*)(xr + cb - 4);
    float4 b = *(const float4*)(xr + cb);
    float4 c = *(const float4*)(xr + cb + 4);
    v[0] = a.x; v[1] = a.y; v[2] = a.z; v[3] = a.w;
    v[4] = b.x; v[5] = b.y; v[6] = b.z; v[7] = b.w;
    v[8] = c.x; v[9] = c.y; v[10] = c.z; v[11] = c.w;
  } else {
    v[0] = 0.f; v[11] = 0.f;
#pragma unroll
    for (int t = 1; t <= 10; ++t) v[t] = xr[refl(cb - 4 + t, Wd)];
  }
#pragma unroll
  for (int k = 0; k < 4; ++k) {
    float a0 = 0.f, a1 = 0.f;
#pragma unroll
    for (int j = 0; j < 5; ++j) a0 += f0[j] * v[k + 2 + j];
#pragma unroll
    for (int j = 0; j < 7; ++j) a1 += f1[j] * v[k + 1 + j];
    o0[k] = a0; o1[k] = a1;
  }
}

// ---------------------------------------------------------------------------
// Stage A: fused j1 on x (8,3,512,512). Tile half-res 16x32 (full 32x64).
// Writes s0 (full-res ll) and pb (N,18,256,256) orientation mags.
// ---------------------------------------------------------------------------
#define A_RF 38
#define A_PAD 68

__global__ __launch_bounds__(256) void k_fused_j1a(
    const float* __restrict__ x,
    const float* __restrict__ h0, const float* __restrict__ h1,
    float* __restrict__ s0, float* __restrict__ pb) {
  constexpr int H = 512, W = 512;
  __shared__ float lo_s[A_RF][A_PAD];
  __shared__ float hi_s[A_RF][A_PAD];
  int p = blockIdx.x >> 7;        // 128 tiles/plane
  int tloc = blockIdx.x & 127;
  int th = tloc >> 3, tw = tloc & 7;  // tilesW = 8
  int h2_0 = th << 4, w2_0 = tw << 5;
  int c0 = w2_0 << 1;
  const float* xp = x + (size_t)p * (H * W);
  float f0[5], f1[7];
#pragma unroll
  for (int j = 0; j < 5; ++j) f0[j] = h0[j];
#pragma unroll
  for (int j = 0; j < 7; ++j) f1[j] = h1[j];
  int tid = threadIdx.x;

  // Phase 1: row filter -> LDS (38 rows x 64 cols, 16 groups of 4)
  for (int e = tid; e < A_RF * 16; e += 256) {
    int r = e >> 4, g = e & 15;
    int row = refl((h2_0 << 1) - 3 + r, H);
    const float* xr = xp + (size_t)row * W;
    int cb = c0 + (g << 2);
    float o0[4], o1[4];
    rowfilt4(xr, cb, W, f0, f1, o0, o1);
    *(float4*)&lo_s[r][g << 2] = make_float4(o0[0], o0[1], o0[2], o0[3]);
    *(float4*)&hi_s[r][g << 2] = make_float4(o1[0], o1[1], o1[2], o1[3]);
  }
  __syncthreads();

  // Phase 2: col filter + q2c + mag (512 outputs, 2 per thread)
  int n = p / 3, ch = p - 3 * n;
  float* s0p = s0 + (size_t)p * (H * W);
  constexpr size_t sp2 = 256 * 256;
  float* pbb = pb + (size_t)n * 18 * sp2;
#pragma unroll
  for (int it = 0; it < 2; ++it) {
    int o = tid + (it << 8);
    int h2l = o >> 5, w2l = o & 31;
    int h2 = h2_0 + h2l, w2 = w2_0 + w2l;
    float llq[2][2], lhv[2][2], hlv[2][2], hhv[2][2];
#pragma unroll
    for (int dc = 0; dc < 2; ++dc) {
      int cl = (w2l << 1) + dc;
      float vl[8], vh[8];
#pragma unroll
      for (int tt = 0; tt < 8; ++tt) {
        vl[tt] = lo_s[(h2l << 1) + tt][cl];
        vh[tt] = hi_s[(h2l << 1) + tt][cl];
      }
#pragma unroll
      for (int dr = 0; dr < 2; ++dr) {
        float sll = 0.f, slh = 0.f, shl = 0.f, shh = 0.f;
#pragma unroll
        for (int j = 0; j < 5; ++j) {
          sll += f0[j] * vl[dr + 1 + j];
          shl += f0[j] * vh[dr + 1 + j];
        }
#pragma unroll
        for (int j = 0; j < 7; ++j) {
          slh += f1[j] * vl[dr + j];
          shh += f1[j] * vh[dr + j];
        }
        llq[dr][dc] = sll; lhv[dr][dc] = slh; hlv[dr][dc] = shl; hhv[dr][dc] = shh;
      }
    }
#pragma unroll
    for (int dr = 0; dr < 2; ++dr) {
      *(float2*)&s0p[(size_t)((h2 << 1) + dr) * W + (w2 << 1)] =
          make_float2(llq[dr][0], llq[dr][1]);
    }
    float m[6];
    q2c_mag(lhv, &m[0], &m[5]);
    q2c_mag(hhv, &m[1], &m[4]);
    q2c_mag(hlv, &m[2], &m[3]);
#pragma unroll
    for (int o6 = 0; o6 < 6; ++o6) {
      pbb[(size_t)(o6 * 3 + ch) * sp2 + ((size_t)h2 << 8) + w2] = m[o6];
    }
  }
}

// ---------------------------------------------------------------------------
// Stage B: fused j2 on s0 (24,512,512). Tile quarter-res 16x16.
// Writes pooled ll (q=ch) and 6 mags (q=(7+o)*3+ch) to out.
// ---------------------------------------------------------------------------
#define B_R 80
#define B_PAD 36

__global__ __launch_bounds__(256) void k_fused_j2(
    const float* __restrict__ s0,
    const float* __restrict__ h0a, const float* __restrict__ h0b,
    const float* __restrict__ h1a, const float* __restrict__ h1b,
    float* __restrict__ out) {
  constexpr int H = 512, W = 512;
  __shared__ float lo2_s[B_R][B_PAD];
  __shared__ float hi2_s[B_R][B_PAD];
  int p = blockIdx.x >> 6;        // 64 tiles/plane
  int tloc = blockIdx.x & 63;
  int th = tloc >> 3, tw = tloc & 7;
  int h4_0 = th << 4, w4_0 = tw << 4;
  const float* sp = s0 + (size_t)p * (H * W);
  float fa0[10], fb0[10], fa1[10], fb1[10];
#pragma unroll
  for (int j = 0; j < 10; ++j) {
    fa0[j] = h0a[j]; fb0[j] = h0b[j]; fa1[j] = h1a[j]; fb1[j] = h1b[j];
  }
  int tid = threadIdx.x;

  // Phase 1: row dfilt -> LDS (80 rows x 16 col-pairs), 5 iters
  for (int e = tid; e < B_R * 16; e += 256) {
    int hr = e >> 4, il = e & 15;
    int row = refl((h4_0 << 2) - 8 + hr, H);
    const float* xr = sp + (size_t)row * W;
    int i = w4_0 + il;
    int base = (i << 2) - 8;
    float ya0 = 0.f, yb0 = 0.f, ya1 = 0.f, yb1 = 0.f;
    if (base >= 0 && base + 20 <= W) {
      const float* xb = xr + base;
      float4 q0 = *(const float4*)(xb);
      float4 q1 = *(const float4*)(xb + 4);
      float4 q2 = *(const float4*)(xb + 8);
      float4 q3 = *(const float4*)(xb + 12);
      float4 q4 = *(const float4*)(xb + 16);
      float v[20] = {q0.x, q0.y, q0.z, q0.w, q1.x, q1.y, q1.z, q1.w,
                     q2.x, q2.y, q2.z, q2.w, q3.x, q3.y, q3.z, q3.w,
                     q4.x, q4.y, q4.z, q4.w};
#pragma unroll
      for (int j = 0; j < 10; ++j) {
        float ve = v[2 * j], vo = v[2 * j + 1];
        ya0 += fa0[j] * ve; yb0 += fb0[j] * vo;
        ya1 += fa1[j] * ve; yb1 += fb1[j] * vo;
      }
    } else {
#pragma unroll
      for (int j = 0; j < 10; ++j) {
        float ve = xr[refl(base + 2 * j, W)];
        float vo = xr[refl(base + 2 * j + 1, W)];
        ya0 += fa0[j] * ve; yb0 += fb0[j] * vo;
        ya1 += fa1[j] * ve; yb1 += fb1[j] * vo;
      }
    }
    *(float2*)&lo2_s[hr][il << 1] = make_float2(ya0, yb0);
    *(float2*)&hi2_s[hr][il << 1] = make_float2(yb1, ya1);  // highpass: first=yb
  }
  __syncthreads();

  // Phase 2: col dfilt + q2c + mag + pooled ll (1 output/thread)
  {
    int h4l = tid >> 4, w4l = tid & 15;
    int h4 = h4_0 + h4l, w4 = w4_0 + w4l;
    float llv[2][2], lhv[2][2], hlv[2][2], hhv[2][2];
#pragma unroll
    for (int dc = 0; dc < 2; ++dc) {
      int cl = (w4l << 1) + dc;
      float a0l = 0.f, b0l = 0.f, a1l = 0.f, b1l = 0.f;
      float a0h = 0.f, b0h = 0.f, a1h = 0.f, b1h = 0.f;
#pragma unroll
      for (int j = 0; j < 10; ++j) {
        int hre = (h4l << 2) + 2 * j;
        float vel = lo2_s[hre][cl], vol = lo2_s[hre + 1][cl];
        float veh = hi2_s[hre][cl], voh = hi2_s[hre + 1][cl];
        a0l += fa0[j] * vel; b0l += fb0[j] * vol;
        a1l += fa1[j] * vel; b1l += fb1[j] * vol;
        a0h += fa0[j] * veh; b0h += fb0[j] * voh;
        a1h += fa1[j] * veh; b1h += fb1[j] * voh;
      }
      llv[0][dc] = a0l; llv[1][dc] = b0l;
      lhv[0][dc] = b1l; lhv[1][dc] = a1l;
      hlv[0][dc] = a0h; hlv[1][dc] = b0h;
      hhv[0][dc] = b1h; hhv[1][dc] = a1h;
    }
    int n = p / 3, ch = p - 3 * n;
    constexpr size_t spo = 128 * 128;
    float* ob = out + (size_t)n * 147 * spo + ((size_t)h4 << 7) + w4;
    ob[(size_t)ch * spo] = 0.25f * (llv[0][0] + llv[0][1] + llv[1][0] + llv[1][1]);
    float m[6];
    q2c_mag(lhv, &m[0], &m[5]);
    q2c_mag(hhv, &m[1], &m[4]);
    q2c_mag(hlv, &m[2], &m[3]);
#pragma unroll
    for (int o = 0; o < 6; ++o) {
      ob[(size_t)((7 + o) * 3 + ch) * spo] = m[o];
    }
  }
}

// ---------------------------------------------------------------------------
// Stage C: fused j1 on pb (8,18,256,256). Tile half-res 16x32.
// Writes pooled ll (q=(1+o1)*3+ch) and s2 mags (q=(13+o2*6+o1)*3+ch).
// ---------------------------------------------------------------------------
__global__ __launch_bounds__(256) void k_fused_j1c(
    const float* __restrict__ pb,
    const float* __restrict__ h0, const float* __restrict__ h1,
    float* __restrict__ out) {
  constexpr int H = 256, W = 256;
  __shared__ float lo_s[A_RF][A_PAD];
  __shared__ float hi_s[A_RF][A_PAD];
  int p = blockIdx.x >> 5;        // 32 tiles/plane
  int tloc = blockIdx.x & 31;
  int th = tloc >> 2, tw = tloc & 3;  // tilesW = 4
  int h2_0 = th << 4, w2_0 = tw << 5;
  int c0 = w2_0 << 1;
  const float* xp = pb + (size_t)p * (H * W);
  float f0[5], f1[7];
#pragma unroll
  for (int j = 0; j < 5; ++j) f0[j] = h0[j];
#pragma unroll
  for (int j = 0; j < 7; ++j) f1[j] = h1[j];
  int tid = threadIdx.x;

  for (int e = tid; e < A_RF * 16; e += 256) {
    int r = e >> 4, g = e & 15;
    int row = refl((h2_0 << 1) - 3 + r, H);
    const float* xr = xp + (size_t)row * W;
    int cb = c0 + (g << 2);
    float o0[4], o1[4];
    rowfilt4(xr, cb, W, f0, f1, o0, o1);
    *(float4*)&lo_s[r][g << 2] = make_float4(o0[0], o0[1], o0[2], o0[3]);
    *(float4*)&hi_s[r][g << 2] = make_float4(o1[0], o1[1], o1[2], o1[3]);
  }
  __syncthreads();

  int c18 = p % 18, n = p / 18;
  int o1i = c18 / 3, ch = c18 - 3 * o1i;
  constexpr size_t spo = 128 * 128;
  float* ob = out + (size_t)n * 147 * spo;
#pragma unroll
  for (int it = 0; it < 2; ++it) {
    int o = tid + (it << 8);
    int h2l = o >> 5, w2l = o & 31;
    int h2 = h2_0 + h2l, w2 = w2_0 + w2l;
    float llq[2][2], lhv[2][2], hlv[2][2], hhv[2][2];
#pragma unroll
    for (int dc = 0; dc < 2; ++dc) {
      int cl = (w2l << 1) + dc;
      float vl[8], vh[8];
#pragma unroll
      for (int tt = 0; tt < 8; ++tt) {
        vl[tt] = lo_s[(h2l << 1) + tt][cl];
        vh[tt] = hi_s[(h2l << 1) + tt][cl];
      }
#pragma unroll
      for (int dr = 0; dr < 2; ++dr) {
        float sll = 0.f, slh = 0.f, shl = 0.f, shh = 0.f;
#pragma unroll
        for (int j = 0; j < 5; ++j) {
          sll += f0[j] * vl[dr + 1 + j];
          shl += f0[j] * vh[dr + 1 + j];
        }
#pragma unroll
        for (int j = 0; j < 7; ++j) {
          slh += f1[j] * vl[dr + j];
          shh += f1[j] * vh[dr + j];
        }
        llq[dr][dc] = sll; lhv[dr][dc] = slh; hlv[dr][dc] = shl; hhv[dr][dc] = shh;
      }
    }
    size_t px = ((size_t)h2 << 7) + w2;
    ob[(size_t)((1 + o1i) * 3 + ch) * spo + px] =
        0.25f * (llq[0][0] + llq[0][1] + llq[1][0] + llq[1][1]);
    float m[6];
    q2c_mag(lhv, &m[0], &m[5]);
    q2c_mag(hhv, &m[1], &m[4]);
    q2c_mag(hlv, &m[2], &m[3]);
#pragma unroll
    for (int o2 = 0; o2 < 6; ++o2) {
      ob[(size_t)((13 + o2 * 6 + o1i) * 3 + ch) * spo + px] = m[o2];
    }
  }
}

extern "C" void kernel_launch(void* const* d_in, const int* in_sizes, int n_in,
                              void* d_out, int out_size, void* d_ws, size_t ws_size,
                              hipStream_t stream) {
  const float* x   = (const float*)d_in[0];
  const float* h0o = (const float*)d_in[1];
  const float* h1o = (const float*)d_in[2];
  const float* h0a = (const float*)d_in[3];
  const float* h0b = (const float*)d_in[4];
  const float* h1a = (const float*)d_in[5];
  const float* h1b = (const float*)d_in[6];
  float* out = (float*)d_out;
  char* ws = (char*)d_ws;
  (void)in_sizes; (void)n_in; (void)out_size; (void)ws_size;

  const size_t SZ_S0 = (size_t)24 * 512 * 512 * sizeof(float);
  float* s0 = (float*)ws;
  float* pb = (float*)(ws + SZ_S0);

  k_fused_j1a<<<3072, 256, 0, stream>>>(x, h0o, h1o, s0, pb);
  k_fused_j2<<<1536, 256, 0, stream>>>(s0, h0a, h0b, h1a, h1b, out);
  k_fused_j1c<<<4608, 256, 0, stream>>>(pb, h0o, h1o, out);
}

// Round 4
// 70.936 us; speedup vs baseline: 2.3982x; 1.1364x over previous
//
#include <hip/hip_runtime.h>
#include <math.h>

#define MAGB 0.01f

__device__ __forceinline__ int refl(int i, int n) {
  if (i < 0) i = -1 - i;
  if (i >= n) i = 2 * n - 1 - i;
  return i;
}

__device__ __forceinline__ float magf(float re, float im) {
  return sqrtf(re * re + im * im + MAGB * MAGB) - MAGB;
}

// Row-filter 4 adjacent outputs (cols cb..cb+3) for 5-tap f0 and 7-tap f1.
__device__ __forceinline__ void rowfilt4(const float* __restrict__ xr, int cb, int Wd,
                                         const float* __restrict__ f0,
                                         const float* __restrict__ f1,
                                         float* o0, float* o1) {
  float v[12];
  if (cb >= 4 && cb + 8 <= Wd) {
    float4 a = *(const float4*)(xr + cb - 4);
    float4 b = *(const float4*)(xr + cb);
    float4 c = *(const float4*)(xr + cb + 4);
    v[0] = a.x; v[1] = a.y; v[2] = a.z; v[3] = a.w;
    v[4] = b.x; v[5] = b.y; v[6] = b.z; v[7] = b.w;
    v[8] = c.x; v[9] = c.y; v[10] = c.z; v[11] = c.w;
  } else {
    v[0] = 0.f; v[11] = 0.f;
#pragma unroll
    for (int t = 1; t <= 10; ++t) v[t] = xr[refl(cb - 4 + t, Wd)];
  }
#pragma unroll
  for (int k = 0; k < 4; ++k) {
    float a0 = 0.f, a1 = 0.f;
#pragma unroll
    for (int j = 0; j < 5; ++j) a0 += f0[j] * v[k + 2 + j];
#pragma unroll
    for (int j = 0; j < 7; ++j) a1 += f1[j] * v[k + 1 + j];
    o0[k] = a0; o1[k] = a1;
  }
}

#define A_RF 38
#define A_PAD 68

// Phase 2 core for j1 stages: streaming column filter over an 8-row window of
// 4 LDS columns. Produces ll/lh/hl/hh [dr][col] for a horizontal output pair.
struct J1Acc {
  float ll[2][4], lh[2][4], hl[2][4], hh[2][4];
};

__device__ __forceinline__ void j1_colfilt_pair(
    const float (*lo_s)[A_PAD], const float (*hi_s)[A_PAD],
    int h2l, int w2p, const float* __restrict__ f0, const float* __restrict__ f1,
    J1Acc* A) {
#pragma unroll
  for (int dr = 0; dr < 2; ++dr)
#pragma unroll
    for (int c = 0; c < 4; ++c) {
      A->ll[dr][c] = 0.f; A->lh[dr][c] = 0.f; A->hl[dr][c] = 0.f; A->hh[dr][c] = 0.f;
    }
#pragma unroll
  for (int tt = 0; tt < 8; ++tt) {
    float4 lv4 = *(const float4*)&lo_s[(h2l << 1) + tt][w2p << 2];
    float4 hv4 = *(const float4*)&hi_s[(h2l << 1) + tt][w2p << 2];
    float lv[4] = {lv4.x, lv4.y, lv4.z, lv4.w};
    float hv[4] = {hv4.x, hv4.y, hv4.z, hv4.w};
#pragma unroll
    for (int dr = 0; dr < 2; ++dr) {
      int j0 = tt - dr - 1;  // 5-tap index
      int j1 = tt - dr;      // 7-tap index
#pragma unroll
      for (int c = 0; c < 4; ++c) {
        if (j0 >= 0 && j0 < 5) {
          A->ll[dr][c] += f0[j0] * lv[c];
          A->hl[dr][c] += f0[j0] * hv[c];
        }
        if (j1 >= 0 && j1 < 7) {
          A->lh[dr][c] += f1[j1] * lv[c];
          A->hh[dr][c] += f1[j1] * hv[c];
        }
      }
    }
  }
}

// q2c+mag for output k (cols 2k,2k+1) of a [dr][4] block.
__device__ __forceinline__ void q2c_mag_k(const float v[2][4], int k,
                                          float* mlo, float* mhi) {
  float a = v[0][2 * k], b = v[0][2 * k + 1], c = v[1][2 * k], d = v[1][2 * k + 1];
  *mlo = magf((a + d) * 0.5f, (b - c) * 0.5f);
  *mhi = magf((a - d) * 0.5f, (b + c) * 0.5f);
}

// ---------------------------------------------------------------------------
// Stage A: fused j1 on x (8,3,512,512). Tile half-res 16x32.
// ---------------------------------------------------------------------------
__global__ __launch_bounds__(256) void k_fused_j1a(
    const float* __restrict__ x,
    const float* __restrict__ h0, const float* __restrict__ h1,
    float* __restrict__ s0, float* __restrict__ pb) {
  constexpr int H = 512, W = 512;
  __shared__ float lo_s[A_RF][A_PAD];
  __shared__ float hi_s[A_RF][A_PAD];
  int p = blockIdx.x >> 7;
  int tloc = blockIdx.x & 127;
  int th = tloc >> 3, tw = tloc & 7;
  int h2_0 = th << 4, w2_0 = tw << 5;
  int c0 = w2_0 << 1;
  const float* xp = x + (size_t)p * (H * W);
  float f0[5], f1[7];
#pragma unroll
  for (int j = 0; j < 5; ++j) f0[j] = h0[j];
#pragma unroll
  for (int j = 0; j < 7; ++j) f1[j] = h1[j];
  int tid = threadIdx.x;

  // Phase 1: row filter -> LDS
  for (int e = tid; e < A_RF * 16; e += 256) {
    int r = e >> 4, g = e & 15;
    int row = refl((h2_0 << 1) - 3 + r, H);
    const float* xr = xp + (size_t)row * W;
    float o0[4], o1[4];
    rowfilt4(xr, c0 + (g << 2), W, f0, f1, o0, o1);
    *(float4*)&lo_s[r][g << 2] = make_float4(o0[0], o0[1], o0[2], o0[3]);
    *(float4*)&hi_s[r][g << 2] = make_float4(o1[0], o1[1], o1[2], o1[3]);
  }
  __syncthreads();

  // Phase 2: one output-pair per thread (16 x 16 pairs)
  int n = p / 3, ch = p - 3 * n;
  float* s0p = s0 + (size_t)p * (H * W);
  constexpr size_t sp2 = 256 * 256;
  float* pbb = pb + (size_t)n * 18 * sp2;
  int h2l = tid >> 4, w2p = tid & 15;
  int h2 = h2_0 + h2l;
  int w2 = w2_0 + (w2p << 1);
  J1Acc A;
  j1_colfilt_pair(lo_s, hi_s, h2l, w2p, f0, f1, &A);
#pragma unroll
  for (int dr = 0; dr < 2; ++dr) {
    *(float4*)&s0p[(size_t)((h2 << 1) + dr) * W + (w2 << 1)] =
        make_float4(A.ll[dr][0], A.ll[dr][1], A.ll[dr][2], A.ll[dr][3]);
  }
  float m2[6][2];
#pragma unroll
  for (int k = 0; k < 2; ++k) {
    q2c_mag_k(A.lh, k, &m2[0][k], &m2[5][k]);
    q2c_mag_k(A.hh, k, &m2[1][k], &m2[4][k]);
    q2c_mag_k(A.hl, k, &m2[2][k], &m2[3][k]);
  }
#pragma unroll
  for (int o6 = 0; o6 < 6; ++o6) {
    *(float2*)&pbb[(size_t)(o6 * 3 + ch) * sp2 + ((size_t)h2 << 8) + w2] =
        make_float2(m2[o6][0], m2[o6][1]);
  }
}

// ---------------------------------------------------------------------------
// Stage B: fused j2 on s0 (24,512,512). Tile quarter-res 16x16.
// ---------------------------------------------------------------------------
#define B_R 80
#define B_PAD 36

__global__ __launch_bounds__(256) void k_fused_j2(
    const float* __restrict__ s0,
    const float* __restrict__ h0a, const float* __restrict__ h0b,
    const float* __restrict__ h1a, const float* __restrict__ h1b,
    float* __restrict__ out) {
  constexpr int H = 512, W = 512;
  __shared__ float lo2_s[B_R][B_PAD];
  __shared__ float hi2_s[B_R][B_PAD];
  int p = blockIdx.x >> 6;
  int tloc = blockIdx.x & 63;
  int th = tloc >> 3, tw = tloc & 7;
  int h4_0 = th << 4, w4_0 = tw << 4;
  const float* sp = s0 + (size_t)p * (H * W);
  float fa0[10], fb0[10], fa1[10], fb1[10];
#pragma unroll
  for (int j = 0; j < 10; ++j) {
    fa0[j] = h0a[j]; fb0[j] = h0b[j]; fa1[j] = h1a[j]; fb1[j] = h1b[j];
  }
  int tid = threadIdx.x;

  // Phase 1: row dfilt -> LDS; each iter: column-pair (4 outputs) from 6 float4s
  for (int e = tid; e < B_R * 8; e += 256) {
    int hr = e >> 3, g = e & 7;
    int row = refl((h4_0 << 2) - 8 + hr, H);
    const float* xr = sp + (size_t)row * W;
    int i0 = w4_0 + (g << 1);
    int base = (i0 << 2) - 8;
    float v[24];
    if (base >= 0 && base + 24 <= W) {
      const float* xb = xr + base;
#pragma unroll
      for (int q = 0; q < 6; ++q) {
        float4 t = *(const float4*)(xb + (q << 2));
        v[4 * q] = t.x; v[4 * q + 1] = t.y; v[4 * q + 2] = t.z; v[4 * q + 3] = t.w;
      }
    } else {
#pragma unroll
      for (int t = 0; t < 24; ++t) v[t] = xr[refl(base + t, W)];
    }
    float r0[4], r1[4];
#pragma unroll
    for (int k = 0; k < 2; ++k) {
      float ya0 = 0.f, yb0 = 0.f, ya1 = 0.f, yb1 = 0.f;
#pragma unroll
      for (int j = 0; j < 10; ++j) {
        float ve = v[4 * k + 2 * j], vo = v[4 * k + 2 * j + 1];
        ya0 += fa0[j] * ve; yb0 += fb0[j] * vo;
        ya1 += fa1[j] * ve; yb1 += fb1[j] * vo;
      }
      r0[2 * k] = ya0; r0[2 * k + 1] = yb0;
      r1[2 * k] = yb1; r1[2 * k + 1] = ya1;  // highpass: first=yb
    }
    *(float4*)&lo2_s[hr][g << 2] = make_float4(r0[0], r0[1], r0[2], r0[3]);
    *(float4*)&hi2_s[hr][g << 2] = make_float4(r1[0], r1[1], r1[2], r1[3]);
  }
  __syncthreads();

  // Phase 2: col dfilt + q2c + mag + pooled ll (1 output/thread), float2 reads
  {
    int h4l = tid >> 4, w4l = tid & 15;
    int h4 = h4_0 + h4l, w4 = w4_0 + w4l;
    int cl = w4l << 1;
    float a0l[2] = {0.f, 0.f}, b0l[2] = {0.f, 0.f}, a1l[2] = {0.f, 0.f}, b1l[2] = {0.f, 0.f};
    float a0h[2] = {0.f, 0.f}, b0h[2] = {0.f, 0.f}, a1h[2] = {0.f, 0.f}, b1h[2] = {0.f, 0.f};
#pragma unroll
    for (int j = 0; j < 10; ++j) {
      int hre = (h4l << 2) + 2 * j;
      float2 le = *(const float2*)&lo2_s[hre][cl];
      float2 lo_ = *(const float2*)&lo2_s[hre + 1][cl];
      float2 he = *(const float2*)&hi2_s[hre][cl];
      float2 ho = *(const float2*)&hi2_s[hre + 1][cl];
      a0l[0] += fa0[j] * le.x;  a0l[1] += fa0[j] * le.y;
      b0l[0] += fb0[j] * lo_.x; b0l[1] += fb0[j] * lo_.y;
      a1l[0] += fa1[j] * le.x;  a1l[1] += fa1[j] * le.y;
      b1l[0] += fb1[j] * lo_.x; b1l[1] += fb1[j] * lo_.y;
      a0h[0] += fa0[j] * he.x;  a0h[1] += fa0[j] * he.y;
      b0h[0] += fb0[j] * ho.x;  b0h[1] += fb0[j] * ho.y;
      a1h[0] += fa1[j] * he.x;  a1h[1] += fa1[j] * he.y;
      b1h[0] += fb1[j] * ho.x;  b1h[1] += fb1[j] * ho.y;
    }
    float llv[2][2], lhv[2][2], hlv[2][2], hhv[2][2];
#pragma unroll
    for (int dc = 0; dc < 2; ++dc) {
      llv[0][dc] = a0l[dc]; llv[1][dc] = b0l[dc];
      lhv[0][dc] = b1l[dc]; lhv[1][dc] = a1l[dc];
      hlv[0][dc] = a0h[dc]; hlv[1][dc] = b0h[dc];
      hhv[0][dc] = b1h[dc]; hhv[1][dc] = a1h[dc];
    }
    int n = p / 3, ch = p - 3 * n;
    constexpr size_t spo = 128 * 128;
    float* ob = out + (size_t)n * 147 * spo + ((size_t)h4 << 7) + w4;
    ob[(size_t)ch * spo] = 0.25f * (llv[0][0] + llv[0][1] + llv[1][0] + llv[1][1]);
    float m[6];
    { float a = lhv[0][0], b = lhv[0][1], c = lhv[1][0], d = lhv[1][1];
      m[0] = magf((a + d) * 0.5f, (b - c) * 0.5f);
      m[5] = magf((a - d) * 0.5f, (b + c) * 0.5f); }
    { float a = hhv[0][0], b = hhv[0][1], c = hhv[1][0], d = hhv[1][1];
      m[1] = magf((a + d) * 0.5f, (b - c) * 0.5f);
      m[4] = magf((a - d) * 0.5f, (b + c) * 0.5f); }
    { float a = hlv[0][0], b = hlv[0][1], c = hlv[1][0], d = hlv[1][1];
      m[2] = magf((a + d) * 0.5f, (b - c) * 0.5f);
      m[3] = magf((a - d) * 0.5f, (b + c) * 0.5f); }
#pragma unroll
    for (int o = 0; o < 6; ++o) {
      ob[(size_t)((7 + o) * 3 + ch) * spo] = m[o];
    }
  }
}

// ---------------------------------------------------------------------------
// Stage C: fused j1 on pb (8,18,256,256). Tile half-res 16x32.
// ---------------------------------------------------------------------------
__global__ __launch_bounds__(256) void k_fused_j1c(
    const float* __restrict__ pb,
    const float* __restrict__ h0, const float* __restrict__ h1,
    float* __restrict__ out) {
  constexpr int H = 256, W = 256;
  __shared__ float lo_s[A_RF][A_PAD];
  __shared__ float hi_s[A_RF][A_PAD];
  int p = blockIdx.x >> 5;
  int tloc = blockIdx.x & 31;
  int th = tloc >> 2, tw = tloc & 3;
  int h2_0 = th << 4, w2_0 = tw << 5;
  int c0 = w2_0 << 1;
  const float* xp = pb + (size_t)p * (H * W);
  float f0[5], f1[7];
#pragma unroll
  for (int j = 0; j < 5; ++j) f0[j] = h0[j];
#pragma unroll
  for (int j = 0; j < 7; ++j) f1[j] = h1[j];
  int tid = threadIdx.x;

  for (int e = tid; e < A_RF * 16; e += 256) {
    int r = e >> 4, g = e & 15;
    int row = refl((h2_0 << 1) - 3 + r, H);
    const float* xr = xp + (size_t)row * W;
    float o0[4], o1[4];
    rowfilt4(xr, c0 + (g << 2), W, f0, f1, o0, o1);
    *(float4*)&lo_s[r][g << 2] = make_float4(o0[0], o0[1], o0[2], o0[3]);
    *(float4*)&hi_s[r][g << 2] = make_float4(o1[0], o1[1], o1[2], o1[3]);
  }
  __syncthreads();

  int c18 = p % 18, n = p / 18;
  int o1i = c18 / 3, ch = c18 - 3 * o1i;
  constexpr size_t spo = 128 * 128;
  float* ob = out + (size_t)n * 147 * spo;
  int h2l = tid >> 4, w2p = tid & 15;
  int h2 = h2_0 + h2l;
  int w2 = w2_0 + (w2p << 1);
  J1Acc A;
  j1_colfilt_pair(lo_s, hi_s, h2l, w2p, f0, f1, &A);
  size_t px = ((size_t)h2 << 7) + w2;
  // pooled ll pair
  float pl0 = 0.25f * (A.ll[0][0] + A.ll[0][1] + A.ll[1][0] + A.ll[1][1]);
  float pl1 = 0.25f * (A.ll[0][2] + A.ll[0][3] + A.ll[1][2] + A.ll[1][3]);
  *(float2*)&ob[(size_t)((1 + o1i) * 3 + ch) * spo + px] = make_float2(pl0, pl1);
  float m2[6][2];
#pragma unroll
  for (int k = 0; k < 2; ++k) {
    q2c_mag_k(A.lh, k, &m2[0][k], &m2[5][k]);
    q2c_mag_k(A.hh, k, &m2[1][k], &m2[4][k]);
    q2c_mag_k(A.hl, k, &m2[2][k], &m2[3][k]);
  }
#pragma unroll
  for (int o2 = 0; o2 < 6; ++o2) {
    *(float2*)&ob[(size_t)((13 + o2 * 6 + o1i) * 3 + ch) * spo + px] =
        make_float2(m2[o2][0], m2[o2][1]);
  }
}

extern "C" void kernel_launch(void* const* d_in, const int* in_sizes, int n_in,
                              void* d_out, int out_size, void* d_ws, size_t ws_size,
                              hipStream_t stream) {
  const float* x   = (const float*)d_in[0];
  const float* h0o = (const float*)d_in[1];
  const float* h1o = (const float*)d_in[2];
  const float* h0a = (const float*)d_in[3];
  const float* h0b = (const float*)d_in[4];
  const float* h1a = (const float*)d_in[5];
  const float* h1b = (const float*)d_in[6];
  float* out = (float*)d_out;
  char* ws = (char*)d_ws;
  (void)in_sizes; (void)n_in; (void)out_size; (void)ws_size;

  const size_t SZ_S0 = (size_t)24 * 512 * 512 * sizeof(float);
  float* s0 = (float*)ws;
  float* pb = (float*)(ws + SZ_S0);

  k_fused_j1a<<<3072, 256, 0, stream>>>(x, h0o, h1o, s0, pb);
  k_fused_j2<<<1536, 256, 0, stream>>>(s0, h0a, h0b, h1a, h1b, out);
  k_fused_j1c<<<4608, 256, 0, stream>>>(pb, h0o, h1o, out);
}